// Round 12
// baseline (464.496 us; speedup 1.0000x reference)
//
#include <hip/hip_runtime.h>

#define NUM_USERS 100000
#define NUM_ITEMS 50000
#define N_NODES   150000
#define DIM       64
#define NNZ_E     2400000
#define NQ        4096

#define NB         256                         // row-range buckets
#define RPB        587                         // rows per bucket (256*587=150272>=150000)
#define BCAP       10752                       // capacity: mean 9375 + ~14 sigma
#define EPT        16                          // edges per thread in binA
#define BINA_CHUNK (256 * EPT)                 // 4096 edges per block
#define BINA_BLOCKS ((NNZ_E + BINA_CHUNK - 1) / BINA_CHUNK)  // 586

// ---------------------------------------------------------------------------
// 1) init: x0 = concat(user_emb, item_emb); zero bucket cursors
// ---------------------------------------------------------------------------
__global__ void init_kernel(const float* __restrict__ user_emb,
                            const float* __restrict__ item_emb,
                            float* __restrict__ x0, int* __restrict__ bcur) {
    const int total = N_NODES * DIM;
    const int stride = gridDim.x * blockDim.x;
    const int tid = blockIdx.x * blockDim.x + threadIdx.x;
    for (int i = tid; i < total; i += stride) {
        float v = (i < NUM_USERS * DIM) ? user_emb[i] : item_emb[i - NUM_USERS * DIM];
        x0[i] = v;
    }
    if (tid < NB) bcur[tid] = 0;
}

// ---------------------------------------------------------------------------
// 2) pass A: bin edges into NB row-range buckets with LDS-staged run
//    reservation. Edge payload packed as ((row_local)<<18 | col, val_bits).
// ---------------------------------------------------------------------------
__global__ __launch_bounds__(256) void binA_kernel(const int* __restrict__ rows,
                                                   const int* __restrict__ cols,
                                                   const float* __restrict__ vals,
                                                   int* __restrict__ bcur,
                                                   int2* __restrict__ bucket) {
    __shared__ int hist[NB];
    __shared__ int runbase[NB];
    const int t = threadIdx.x;
    hist[t] = 0;                               // NB == blockDim.x == 256
    __syncthreads();

    const int base = blockIdx.x * BINA_CHUNK;
    unsigned pk[EPT];
    int bb[EPT];
#pragma unroll
    for (int j = 0; j < EPT; ++j) {
        const int idx = base + j * 256 + t;    // coalesced per j
        if (idx < NNZ_E) {
            const unsigned r = (unsigned)rows[idx];
            const unsigned c = (unsigned)cols[idx];
            const unsigned b = r / RPB;        // magic-mul constant division
            bb[j] = (int)b;
            pk[j] = ((r - b * RPB) << 18) | c; // rl(10b) | col(18b)
            atomicAdd(&hist[b], 1);
        } else bb[j] = -1;
    }
    __syncthreads();

    const int h = hist[t];
    runbase[t] = (h > 0) ? atomicAdd(&bcur[t], h) : 0;
    hist[t] = 0;                               // becomes local run cursor
    __syncthreads();

#pragma unroll
    for (int j = 0; j < EPT; ++j) {
        if (bb[j] >= 0) {
            const int idx  = base + j * 256 + t;
            const int ls   = atomicAdd(&hist[bb[j]], 1);
            const int slot = runbase[bb[j]] + ls;
            if (slot < BCAP)                   // statistically impossible overflow
                bucket[(size_t)bb[j] * BCAP + slot] =
                    make_int2((int)pk[j], __float_as_int(vals[idx]));
        }
    }
}

// ---------------------------------------------------------------------------
// 3) exclusive scan of the 256 bucket sizes -> bbase (CSR segment bases)
// ---------------------------------------------------------------------------
__global__ __launch_bounds__(256) void scan_bucket_kernel(const int* __restrict__ bcur,
                                                          int* __restrict__ bbase,
                                                          int* __restrict__ row_ptr) {
    const int t = threadIdx.x;
    const int v = bcur[t];
    int x = v;
    for (int off = 1; off < 64; off <<= 1) {
        const int n = __shfl_up(x, off, 64);
        if ((t & 63) >= off) x += n;
    }
    __shared__ int wsum[4];
    if ((t & 63) == 63) wsum[t >> 6] = x;
    __syncthreads();
    int add = 0;
    for (int i = 0; i < (t >> 6); ++i) add += wsum[i];
    bbase[t] = x + add - v;                    // exclusive
    if (t == 0) row_ptr[N_NODES] = NNZ_E;
}

// ---------------------------------------------------------------------------
// 4) pass B: one block per bucket. LDS row-hist -> LDS scan -> write row_ptr
//    and final dense CSR into this block's exclusive contiguous region.
// ---------------------------------------------------------------------------
__global__ __launch_bounds__(256) void binB_kernel(const int* __restrict__ bcur,
                                                   const int* __restrict__ bbase,
                                                   const int2* __restrict__ bucket,
                                                   int2* __restrict__ csr_pair,
                                                   int* __restrict__ row_ptr) {
    __shared__ int hist[RPB];
    __shared__ int wsum[4];
    const int b = blockIdx.x;
    const int t = threadIdx.x;
    const int size = bcur[b];
    const int sz = size < BCAP ? size : BCAP;
    const size_t base_in = (size_t)b * BCAP;
    const int base_out = bbase[b];

    for (int i = t; i < RPB; i += 256) hist[i] = 0;
    __syncthreads();
    for (int i = t; i < sz; i += 256) {
        const unsigned rl = ((unsigned)bucket[base_in + i].x) >> 18;
        atomicAdd(&hist[rl], 1);
    }
    __syncthreads();

    // exclusive scan of hist[0..RPB): 3 elems/thread + wave/block scan
    const int e0 = t * 3;
    int v0 = (e0 + 0 < RPB) ? hist[e0 + 0] : 0;
    int v1 = (e0 + 1 < RPB) ? hist[e0 + 1] : 0;
    int v2 = (e0 + 2 < RPB) ? hist[e0 + 2] : 0;
    const int s = v0 + v1 + v2;
    int x = s;
    for (int off = 1; off < 64; off <<= 1) {
        const int n = __shfl_up(x, off, 64);
        if ((t & 63) >= off) x += n;
    }
    if ((t & 63) == 63) wsum[t >> 6] = x;
    __syncthreads();                           // all hist reads complete here
    int add = 0;
    for (int i = 0; i < (t >> 6); ++i) add += wsum[i];
    int run = (x - s) + add;                   // exclusive prefix for elem e0

    const int row0 = b * RPB;
    if (e0 + 0 < RPB) { hist[e0 + 0] = run; if (row0 + e0 + 0 < N_NODES) row_ptr[row0 + e0 + 0] = base_out + run; run += v0; }
    if (e0 + 1 < RPB) { hist[e0 + 1] = run; if (row0 + e0 + 1 < N_NODES) row_ptr[row0 + e0 + 1] = base_out + run; run += v1; }
    if (e0 + 2 < RPB) { hist[e0 + 2] = run; if (row0 + e0 + 2 < N_NODES) row_ptr[row0 + e0 + 2] = base_out + run; run += v2; }
    __syncthreads();

    for (int i = t; i < sz; i += 256) {
        const int2 ev = bucket[base_in + i];
        const unsigned rl = ((unsigned)ev.x) >> 18;
        const int slot = atomicAdd(&hist[rl], 1);
        csr_pair[base_out + slot] = make_int2(ev.x & 0x3FFFF, ev.y);
    }
}

// ---------------------------------------------------------------------------
// 5) SpMM pull, MLP-deep variant: one 16-lane group per row (16 rows/block).
//    Each lane owns one float4 column slice; unroll 8 -> 8 independent
//    gathers in flight per lane (2x the previous per-lane MLP). No shfl
//    epilogue; group writes its row directly.
// ---------------------------------------------------------------------------
__global__ __launch_bounds__(256) void spmm_kernel(const int* __restrict__ row_ptr,
                            const int2* __restrict__ csr_pair,
                            const float* __restrict__ x_in, float* __restrict__ x_out) {
    const int lane16 = threadIdx.x & 15;      // lane within group
    const int row    = blockIdx.x * 16 + (threadIdx.x >> 4);
    if (row >= N_NODES) return;
    const int s  = row_ptr[row];
    const int e  = row_ptr[row + 1];
    const int d4 = lane16 * 4;

    float sx = 0.f, sy = 0.f, sz = 0.f, sw = 0.f;
    for (int i = s; i < e; i += 8) {
        int   c[8];
        float v[8];
#pragma unroll
        for (int j = 0; j < 8; ++j) {
            const int idx = i + j;
            int2 ev = (idx < e) ? csr_pair[idx] : make_int2(0, 0);
            c[j] = ev.x;
            v[j] = __int_as_float(ev.y);       // 0 bits -> 0.0f for dummies
        }
#pragma unroll
        for (int j = 0; j < 8; ++j) {
            const float4 xv = *reinterpret_cast<const float4*>(
                &x_in[(size_t)c[j] * DIM + d4]);
            sx += v[j] * xv.x; sy += v[j] * xv.y;
            sz += v[j] * xv.z; sw += v[j] * xv.w;
        }
    }
    float4 r; r.x = sx; r.y = sy; r.z = sz; r.w = sw;
    *reinterpret_cast<float4*>(&x_out[(size_t)row * DIM + d4]) = r;
}

// ---------------------------------------------------------------------------
// 6) gather-accumulate queried rows into d_out: out += 0.25 * x[node]
// ---------------------------------------------------------------------------
template <bool FIRST>
__global__ void gacc_kernel(const float* __restrict__ x, const int* __restrict__ user_ids,
                            const int* __restrict__ item_ids, float* __restrict__ out) {
    const int tid = blockIdx.x * blockDim.x + threadIdx.x;
    if (tid >= 2 * NQ * DIM) return;
    const int i = tid >> 6;
    const int d = tid & 63;
    int node;
    if (i < NQ) node = user_ids[i];
    else        node = NUM_USERS + item_ids[i - NQ];
    float v = 0.25f * x[(size_t)node * DIM + d];
    if (FIRST) out[tid] = v;
    else       out[tid] += v;
}

// ---------------------------------------------------------------------------
extern "C" void kernel_launch(void* const* d_in, const int* in_sizes, int n_in,
                              void* d_out, int out_size, void* d_ws, size_t ws_size,
                              hipStream_t stream) {
    const float* user_emb  = (const float*)d_in[0];
    const float* item_emb  = (const float*)d_in[1];
    const float* edge_vals = (const float*)d_in[2];
    const int*   edge_rows = (const int*)d_in[3];
    const int*   edge_cols = (const int*)d_in[4];
    const int*   user_ids  = (const int*)d_in[5];
    const int*   item_ids  = (const int*)d_in[6];
    float* out = (float*)d_out;

    // workspace carve-up (256B aligned); total ~96.7 MB
    char* ws = (char*)d_ws;
    size_t off = 0;
    auto carve = [&](size_t bytes) {
        char* p = ws + off; off += (bytes + 255) & ~(size_t)255; return p;
    };
    float* x0       = (float*)carve((size_t)N_NODES * DIM * sizeof(float));   // 38.4 MB
    float* x1       = (float*)carve((size_t)N_NODES * DIM * sizeof(float));   // 38.4 MB
    int2*  csr_pair = (int2*) carve((size_t)NNZ_E * sizeof(int2));            // 19.2 MB
    int*   row_ptr  = (int*)  carve((size_t)(N_NODES + 1) * sizeof(int));     // 0.6 MB
    int*   bcur     = (int*)  carve((size_t)NB * sizeof(int));
    int*   bbase    = (int*)  carve((size_t)NB * sizeof(int));
    // bucket staging (22.0 MB) aliased into x1: dead before hop-1 writes x1
    int2*  bucket   = (int2*)x1;
    static_assert((size_t)NB * BCAP * sizeof(int2) <= (size_t)N_NODES * DIM * sizeof(float),
                  "bucket staging must fit inside x1");
    (void)in_sizes; (void)n_in; (void)out_size;

    // Defensive: never write past the provided workspace.
    if (ws_size < off) return;

    const int gth_grid = (2 * NQ * DIM + 255) / 256;

    // 1) init x0 (+ zero bucket cursors)
    hipLaunchKernelGGL(init_kernel, dim3(2048), dim3(256), 0, stream,
                       user_emb, item_emb, x0, bcur);
    // out = 0.25 * x0[queried]
    hipLaunchKernelGGL((gacc_kernel<true>), dim3(gth_grid), dim3(256), 0, stream,
                       x0, user_ids, item_ids, out);
    // 2) pass A: bin edges into buckets (staged in x1's memory)
    hipLaunchKernelGGL(binA_kernel, dim3(BINA_BLOCKS), dim3(256), 0, stream,
                       edge_rows, edge_cols, edge_vals, bcur, bucket);
    // 3) scan bucket sizes -> CSR segment bases
    hipLaunchKernelGGL(scan_bucket_kernel, dim3(1), dim3(256), 0, stream,
                       bcur, bbase, row_ptr);
    // 4) pass B: per-bucket row sort -> row_ptr + dense CSR
    hipLaunchKernelGGL(binB_kernel, dim3(NB), dim3(256), 0, stream,
                       bcur, bbase, bucket, csr_pair, row_ptr);
    // 5) three SpMM hops (ping-pong x0/x1), each followed by gather-accumulate
    const int spmm_grid = (N_NODES + 15) / 16;  // 16 rows (16-lane groups) per block
    float* xin = x0; float* xout = x1;
    for (int h = 0; h < 3; ++h) {
        hipLaunchKernelGGL(spmm_kernel, dim3(spmm_grid), dim3(256), 0, stream,
                           row_ptr, csr_pair, xin, xout);
        hipLaunchKernelGGL((gacc_kernel<false>), dim3(gth_grid), dim3(256), 0, stream,
                           xout, user_ids, item_ids, out);
        float* t = xin; xin = xout; xout = t;
    }
}

// Round 14
// 375.810 us; speedup vs baseline: 1.2360x; 1.2360x over previous
//
#include <hip/hip_runtime.h>
#include <hip/hip_fp16.h>

#define NUM_USERS 100000
#define NUM_ITEMS 50000
#define N_NODES   150000
#define DIM       64
#define NNZ_E     2400000
#define NQ        4096

#define NB         256                         // row-range buckets
#define RPB        587                         // rows per bucket (256*587=150272>=150000)
#define BCAP       10752                       // capacity: mean 9375 + ~14 sigma
#define EPT        16                          // edges per thread in binA
#define BINA_CHUNK (256 * EPT)                 // 4096 edges per block
#define BINA_BLOCKS ((NNZ_E + BINA_CHUNK - 1) / BINA_CHUNK)  // 586

union H4 { __half2 h2[2]; uint2 u; };

// ---------------------------------------------------------------------------
// 1) init: x0 = fp16(concat(user_emb, item_emb)); zero bucket cursors
//    (NUM_USERS*DIM = 6.4M divisible by 4 -> no float4 straddle)
// ---------------------------------------------------------------------------
__global__ void init_kernel(const float* __restrict__ user_emb,
                            const float* __restrict__ item_emb,
                            __half* __restrict__ x0, int* __restrict__ bcur) {
    const int total4 = N_NODES * DIM / 4;
    const int stride = gridDim.x * blockDim.x;
    const int tid = blockIdx.x * blockDim.x + threadIdx.x;
    for (int i = tid; i < total4; i += stride) {
        const int base = i * 4;
        float4 v;
        if (base < NUM_USERS * DIM)
            v = *reinterpret_cast<const float4*>(&user_emb[base]);
        else
            v = *reinterpret_cast<const float4*>(&item_emb[base - NUM_USERS * DIM]);
        H4 o;
        o.h2[0] = __floats2half2_rn(v.x, v.y);
        o.h2[1] = __floats2half2_rn(v.z, v.w);
        *reinterpret_cast<uint2*>(&x0[base]) = o.u;
    }
    if (tid < NB) bcur[tid] = 0;
}

// ---------------------------------------------------------------------------
// 2) pass A: bin edges into NB row-range buckets with LDS-staged run
//    reservation. Edge payload packed as ((row_local)<<18 | col, val_bits).
// ---------------------------------------------------------------------------
__global__ __launch_bounds__(256) void binA_kernel(const int* __restrict__ rows,
                                                   const int* __restrict__ cols,
                                                   const float* __restrict__ vals,
                                                   int* __restrict__ bcur,
                                                   int2* __restrict__ bucket) {
    __shared__ int hist[NB];
    __shared__ int runbase[NB];
    const int t = threadIdx.x;
    hist[t] = 0;                               // NB == blockDim.x == 256
    __syncthreads();

    const int base = blockIdx.x * BINA_CHUNK;
    unsigned pk[EPT];
    int bb[EPT];
#pragma unroll
    for (int j = 0; j < EPT; ++j) {
        const int idx = base + j * 256 + t;    // coalesced per j
        if (idx < NNZ_E) {
            const unsigned r = (unsigned)rows[idx];
            const unsigned c = (unsigned)cols[idx];
            const unsigned b = r / RPB;        // magic-mul constant division
            bb[j] = (int)b;
            pk[j] = ((r - b * RPB) << 18) | c; // rl(10b) | col(18b)
            atomicAdd(&hist[b], 1);
        } else bb[j] = -1;
    }
    __syncthreads();

    const int h = hist[t];
    runbase[t] = (h > 0) ? atomicAdd(&bcur[t], h) : 0;
    hist[t] = 0;                               // becomes local run cursor
    __syncthreads();

#pragma unroll
    for (int j = 0; j < EPT; ++j) {
        if (bb[j] >= 0) {
            const int idx  = base + j * 256 + t;
            const int ls   = atomicAdd(&hist[bb[j]], 1);
            const int slot = runbase[bb[j]] + ls;
            if (slot < BCAP)                   // statistically impossible overflow
                bucket[(size_t)bb[j] * BCAP + slot] =
                    make_int2((int)pk[j], __float_as_int(vals[idx]));
        }
    }
}

// ---------------------------------------------------------------------------
// 3) exclusive scan of the 256 bucket sizes -> bbase (CSR segment bases)
// ---------------------------------------------------------------------------
__global__ __launch_bounds__(256) void scan_bucket_kernel(const int* __restrict__ bcur,
                                                          int* __restrict__ bbase,
                                                          int* __restrict__ row_ptr) {
    const int t = threadIdx.x;
    const int v = bcur[t];
    int x = v;
    for (int off = 1; off < 64; off <<= 1) {
        const int n = __shfl_up(x, off, 64);
        if ((t & 63) >= off) x += n;
    }
    __shared__ int wsum[4];
    if ((t & 63) == 63) wsum[t >> 6] = x;
    __syncthreads();
    int add = 0;
    for (int i = 0; i < (t >> 6); ++i) add += wsum[i];
    bbase[t] = x + add - v;                    // exclusive
    if (t == 0) row_ptr[N_NODES] = NNZ_E;
}

// ---------------------------------------------------------------------------
// 4) pass B: one block per bucket. LDS row-hist -> LDS scan -> write row_ptr
//    and final dense CSR into this block's exclusive contiguous region.
// ---------------------------------------------------------------------------
__global__ __launch_bounds__(256) void binB_kernel(const int* __restrict__ bcur,
                                                   const int* __restrict__ bbase,
                                                   const int2* __restrict__ bucket,
                                                   int2* __restrict__ csr_pair,
                                                   int* __restrict__ row_ptr) {
    __shared__ int hist[RPB];
    __shared__ int wsum[4];
    const int b = blockIdx.x;
    const int t = threadIdx.x;
    const int size = bcur[b];
    const int sz = size < BCAP ? size : BCAP;
    const size_t base_in = (size_t)b * BCAP;
    const int base_out = bbase[b];

    for (int i = t; i < RPB; i += 256) hist[i] = 0;
    __syncthreads();
    for (int i = t; i < sz; i += 256) {
        const unsigned rl = ((unsigned)bucket[base_in + i].x) >> 18;
        atomicAdd(&hist[rl], 1);
    }
    __syncthreads();

    // exclusive scan of hist[0..RPB): 3 elems/thread + wave/block scan
    const int e0 = t * 3;
    int v0 = (e0 + 0 < RPB) ? hist[e0 + 0] : 0;
    int v1 = (e0 + 1 < RPB) ? hist[e0 + 1] : 0;
    int v2 = (e0 + 2 < RPB) ? hist[e0 + 2] : 0;
    const int s = v0 + v1 + v2;
    int x = s;
    for (int off = 1; off < 64; off <<= 1) {
        const int n = __shfl_up(x, off, 64);
        if ((t & 63) >= off) x += n;
    }
    if ((t & 63) == 63) wsum[t >> 6] = x;
    __syncthreads();                           // all hist reads complete here
    int add = 0;
    for (int i = 0; i < (t >> 6); ++i) add += wsum[i];
    int run = (x - s) + add;                   // exclusive prefix for elem e0

    const int row0 = b * RPB;
    if (e0 + 0 < RPB) { hist[e0 + 0] = run; if (row0 + e0 + 0 < N_NODES) row_ptr[row0 + e0 + 0] = base_out + run; run += v0; }
    if (e0 + 1 < RPB) { hist[e0 + 1] = run; if (row0 + e0 + 1 < N_NODES) row_ptr[row0 + e0 + 1] = base_out + run; run += v1; }
    if (e0 + 2 < RPB) { hist[e0 + 2] = run; if (row0 + e0 + 2 < N_NODES) row_ptr[row0 + e0 + 2] = base_out + run; run += v2; }
    __syncthreads();

    for (int i = t; i < sz; i += 256) {
        const int2 ev = bucket[base_in + i];
        const unsigned rl = ((unsigned)ev.x) >> 18;
        const int slot = atomicAdd(&hist[rl], 1);
        csr_pair[base_out + slot] = make_int2(ev.x & 0x3FFFF, ev.y);
    }
}

// ---------------------------------------------------------------------------
// 5) SpMM pull, fp16-x variant: one 16-lane group per row (16 rows/block).
//    Lane owns 4 halves (8B load); fp32 accumulate; fp16 store. 8 edges
//    in flight per lane.
// ---------------------------------------------------------------------------
__global__ __launch_bounds__(256) void spmm_kernel(const int* __restrict__ row_ptr,
                            const int2* __restrict__ csr_pair,
                            const __half* __restrict__ x_in, __half* __restrict__ x_out) {
    const int lane16 = threadIdx.x & 15;      // lane within group
    const int row    = blockIdx.x * 16 + (threadIdx.x >> 4);
    if (row >= N_NODES) return;
    const int s  = row_ptr[row];
    const int e  = row_ptr[row + 1];
    const int d4 = lane16 * 4;                // half-element base

    float sx = 0.f, sy = 0.f, sz = 0.f, sw = 0.f;
    for (int i = s; i < e; i += 8) {
        int   c[8];
        float v[8];
#pragma unroll
        for (int j = 0; j < 8; ++j) {
            const int idx = i + j;
            int2 ev = (idx < e) ? csr_pair[idx] : make_int2(0, 0);
            c[j] = ev.x;
            v[j] = __int_as_float(ev.y);       // 0 bits -> 0.0f for dummies
        }
#pragma unroll
        for (int j = 0; j < 8; ++j) {
            H4 in;
            in.u = *reinterpret_cast<const uint2*>(&x_in[(size_t)c[j] * DIM + d4]);
            const float2 lo = __half22float2(in.h2[0]);
            const float2 hi = __half22float2(in.h2[1]);
            sx += v[j] * lo.x; sy += v[j] * lo.y;
            sz += v[j] * hi.x; sw += v[j] * hi.y;
        }
    }
    H4 o;
    o.h2[0] = __floats2half2_rn(sx, sy);
    o.h2[1] = __floats2half2_rn(sz, sw);
    *reinterpret_cast<uint2*>(&x_out[(size_t)row * DIM + d4]) = o.u;
}

// ---------------------------------------------------------------------------
// 6) gather-accumulate queried rows into d_out: out += 0.25 * x[node]
// ---------------------------------------------------------------------------
template <bool FIRST>
__global__ void gacc_kernel(const __half* __restrict__ x, const int* __restrict__ user_ids,
                            const int* __restrict__ item_ids, float* __restrict__ out) {
    const int tid = blockIdx.x * blockDim.x + threadIdx.x;
    if (tid >= 2 * NQ * DIM) return;
    const int i = tid >> 6;
    const int d = tid & 63;
    int node;
    if (i < NQ) node = user_ids[i];
    else        node = NUM_USERS + item_ids[i - NQ];
    float v = 0.25f * __half2float(x[(size_t)node * DIM + d]);
    if (FIRST) out[tid] = v;
    else       out[tid] += v;
}

// ---------------------------------------------------------------------------
extern "C" void kernel_launch(void* const* d_in, const int* in_sizes, int n_in,
                              void* d_out, int out_size, void* d_ws, size_t ws_size,
                              hipStream_t stream) {
    const float* user_emb  = (const float*)d_in[0];
    const float* item_emb  = (const float*)d_in[1];
    const float* edge_vals = (const float*)d_in[2];
    const int*   edge_rows = (const int*)d_in[3];
    const int*   edge_cols = (const int*)d_in[4];
    const int*   user_ids  = (const int*)d_in[5];
    const int*   item_ids  = (const int*)d_in[6];
    float* out = (float*)d_out;

    // workspace carve-up (256B aligned); total ~80.4 MB (no aliasing now)
    char* ws = (char*)d_ws;
    size_t off = 0;
    auto carve = [&](size_t bytes) {
        char* p = ws + off; off += (bytes + 255) & ~(size_t)255; return p;
    };
    __half* x0      = (__half*)carve((size_t)N_NODES * DIM * sizeof(__half)); // 19.2 MB
    __half* x1      = (__half*)carve((size_t)N_NODES * DIM * sizeof(__half)); // 19.2 MB
    int2*  csr_pair = (int2*)  carve((size_t)NNZ_E * sizeof(int2));           // 19.2 MB
    int2*  bucket   = (int2*)  carve((size_t)NB * BCAP * sizeof(int2));       // 22.0 MB
    int*   row_ptr  = (int*)   carve((size_t)(N_NODES + 1) * sizeof(int));    // 0.6 MB
    int*   bcur     = (int*)   carve((size_t)NB * sizeof(int));
    int*   bbase    = (int*)   carve((size_t)NB * sizeof(int));
    (void)in_sizes; (void)n_in; (void)out_size;

    // Defensive: never write past the provided workspace.
    if (ws_size < off) return;

    const int gth_grid = (2 * NQ * DIM + 255) / 256;

    // 1) init x0 fp16 (+ zero bucket cursors)
    hipLaunchKernelGGL(init_kernel, dim3(2048), dim3(256), 0, stream,
                       user_emb, item_emb, x0, bcur);
    // out = 0.25 * x0[queried]
    hipLaunchKernelGGL((gacc_kernel<true>), dim3(gth_grid), dim3(256), 0, stream,
                       x0, user_ids, item_ids, out);
    // 2) pass A: bin edges into buckets
    hipLaunchKernelGGL(binA_kernel, dim3(BINA_BLOCKS), dim3(256), 0, stream,
                       edge_rows, edge_cols, edge_vals, bcur, bucket);
    // 3) scan bucket sizes -> CSR segment bases
    hipLaunchKernelGGL(scan_bucket_kernel, dim3(1), dim3(256), 0, stream,
                       bcur, bbase, row_ptr);
    // 4) pass B: per-bucket row sort -> row_ptr + dense CSR
    hipLaunchKernelGGL(binB_kernel, dim3(NB), dim3(256), 0, stream,
                       bcur, bbase, bucket, csr_pair, row_ptr);
    // 5) three SpMM hops (ping-pong x0/x1), each followed by gather-accumulate
    const int spmm_grid = (N_NODES + 15) / 16;  // 16 rows (16-lane groups) per block
    __half* xin = x0; __half* xout = x1;
    for (int h = 0; h < 3; ++h) {
        hipLaunchKernelGGL(spmm_kernel, dim3(spmm_grid), dim3(256), 0, stream,
                           row_ptr, csr_pair, xin, xout);
        hipLaunchKernelGGL((gacc_kernel<false>), dim3(gth_grid), dim3(256), 0, stream,
                           xout, user_ids, item_ids, out);
        __half* t = xin; xin = xout; xout = t;
    }
}